// Round 1
// baseline (1246.290 us; speedup 1.0000x reference)
//
#include <hip/hip_runtime.h>

#define EMB   64
#define NCON  50000
#define NVAR  100000
#define NEDGE 1600000
#define EPSLN 1e-5f

// padded-CSR capacities (worst case: every node pads +15)
#define PADEC (NEDGE + 15 * NCON)    // 2,350,000
#define PADEV (NEDGE + 15 * NVAR)    // 3,100,000

typedef _Float16 half2_t __attribute__((ext_vector_type(2)));
typedef _Float16 f16x8  __attribute__((ext_vector_type(8)));

// ---- wave-total via DPP (no DS ops) ----
template <int CTRL, int RMASK>
__device__ __forceinline__ float dpp_add_f(float x) {
    int m = __builtin_amdgcn_update_dpp(0, __builtin_bit_cast(int, x), CTRL, RMASK, 0xf, true);
    return x + __builtin_bit_cast(float, m);
}
__device__ __forceinline__ float wtotal64(float x) {
    x = dpp_add_f<0x111, 0xf>(x);
    x = dpp_add_f<0x112, 0xf>(x);
    x = dpp_add_f<0x114, 0xf>(x);
    x = dpp_add_f<0x118, 0xf>(x);
    x = dpp_add_f<0x142, 0xa>(x);
    x = dpp_add_f<0x143, 0xc>(x);
    return __builtin_bit_cast(float, __builtin_amdgcn_readlane(__builtin_bit_cast(int, x), 63));
}
template <int CTRL, int RMASK>
__device__ __forceinline__ int dpp_add_i(int x) {
    return x + __builtin_amdgcn_update_dpp(0, x, CTRL, RMASK, 0xf, true);
}
__device__ __forceinline__ int wtotal64_i(int x) {
    x = dpp_add_i<0x111, 0xf>(x);
    x = dpp_add_i<0x112, 0xf>(x);
    x = dpp_add_i<0x114, 0xf>(x);
    x = dpp_add_i<0x118, 0xf>(x);
    x = dpp_add_i<0x142, 0xa>(x);
    x = dpp_add_i<0x143, 0xc>(x);
    return __builtin_amdgcn_readlane(x, 63);
}

__device__ __forceinline__ float dot2f(half2_t a, half2_t b, float c) {
    return __builtin_amdgcn_fdot2(a, b, c, false);
}

__device__ __forceinline__ half2_t hmax2(half2_t a, half2_t b) {
#if defined(__has_builtin) && __has_builtin(__builtin_elementwise_max)
    return __builtin_elementwise_max(a, b);
#else
    half2_t r;
    r.x = a.x > b.x ? a.x : b.x;
    r.y = a.y > b.y ? a.y : b.y;
    return r;
#endif
}

// 8 x ds_read_b128 + 32 x v_dot2 with 4 independent accumulator chains
__device__ __forceinline__ float matvec_f16(const _Float16* __restrict__ buf,
                                            const half2_t* __restrict__ wh, float acc) {
    const float4* hp4 = (const float4*)buf;
    float a0 = acc, a1 = 0.0f, a2 = 0.0f, a3 = 0.0f;
#pragma unroll
    for (int j4 = 0; j4 < 8; ++j4) {
        float4 t = hp4[j4];
        a0 = dot2f(wh[4 * j4 + 0], __builtin_bit_cast(half2_t, t.x), a0);
        a1 = dot2f(wh[4 * j4 + 1], __builtin_bit_cast(half2_t, t.y), a1);
        a2 = dot2f(wh[4 * j4 + 2], __builtin_bit_cast(half2_t, t.z), a2);
        a3 = dot2f(wh[4 * j4 + 3], __builtin_bit_cast(half2_t, t.w), a3);
    }
    return (a0 + a1) + (a2 + a3);
}

__device__ __forceinline__ void load_w_f16(const float* __restrict__ W, int stride,
                                           int lane, half2_t* wh) {
#pragma unroll
    for (int j4 = 0; j4 < 16; ++j4) {
        float4 t = *(const float4*)(W + (size_t)lane * stride + j4 * 4);
        wh[2 * j4 + 0] = half2_t{(_Float16)t.x, (_Float16)t.y};
        wh[2 * j4 + 1] = half2_t{(_Float16)t.z, (_Float16)t.w};
    }
}

// ---------------- CSR build ----------------

// both directions in one pass; nontemporal reads keep the edge stream from
// churning L2 (the deg histograms want to stay resident)
__global__ __launch_bounds__(256) void hist2_kernel(
        const int* __restrict__ ci, const int* __restrict__ vi,
        int* __restrict__ degC, int* __restrict__ degV, int E) {
    int i = blockIdx.x * blockDim.x + threadIdx.x;
    for (; i < E; i += gridDim.x * blockDim.x) {
        atomicAdd(&degC[__builtin_nontemporal_load(ci + i)], 1);
        atomicAdd(&degV[__builtin_nontemporal_load(vi + i)], 1);
    }
}

template <bool PAD>
__global__ __launch_bounds__(256) void chunk_sum_kernel(const int* __restrict__ hist,
                                                        int* __restrict__ csum, int N) {
    __shared__ int wpart[4];
    const int base = blockIdx.x * 1024 + threadIdx.x * 4;
    int s = 0;
    if (base + 3 < N) {
        int4 t = *(const int4*)(hist + base);
        if (PAD) s = ((t.x+15)&~15) + ((t.y+15)&~15) + ((t.z+15)&~15) + ((t.w+15)&~15);
        else     s = t.x + t.y + t.z + t.w;
    } else {
#pragma unroll
        for (int j = 0; j < 4; ++j)
            if (base + j < N) { int v = hist[base + j]; s += PAD ? ((v+15)&~15) : v; }
    }
    s = wtotal64_i(s);
    if ((threadIdx.x & 63) == 0) wpart[threadIdx.x >> 6] = s;
    __syncthreads();
    if (threadIdx.x == 0) csum[blockIdx.x] = wpart[0] + wpart[1] + wpart[2] + wpart[3];
}

__global__ void chunk_offsets_kernel(const int* __restrict__ csum, int* __restrict__ coff,
                                     int* __restrict__ rowptr, int nchunk, int N) {
    const int lane = threadIdx.x;
    int carry = 0;
    for (int base = 0; base < nchunk; base += 64) {
        const int i = base + lane;
        int val = (i < nchunk) ? csum[i] : 0;
        int incl = val;
#pragma unroll
        for (int off = 1; off < 64; off <<= 1) {
            int t = __shfl_up(incl, off, 64);
            if (lane >= off) incl += t;
        }
        if (i < nchunk) coff[i] = incl - val + carry;
        carry += __shfl(incl, 63, 64);
    }
    if (lane == 0) rowptr[N] = carry;
}

template <bool PAD>
__global__ __launch_bounds__(256) void chunk_apply_kernel(
        const int* __restrict__ hist, const int* __restrict__ coff,
        int* __restrict__ rowptr, int* __restrict__ cursor, int N) {
    __shared__ int wpart[4];
    const int wv = threadIdx.x >> 6;
    const int lane = threadIdx.x & 63;
    const int base = blockIdx.x * 1024 + threadIdx.x * 4;
    int v0 = 0, v1 = 0, v2 = 0, v3 = 0;
    if (base + 3 < N) {
        int4 t = *(const int4*)(hist + base);
        v0 = t.x; v1 = t.y; v2 = t.z; v3 = t.w;
    } else {
        if (base + 0 < N) v0 = hist[base + 0];
        if (base + 1 < N) v1 = hist[base + 1];
        if (base + 2 < N) v2 = hist[base + 2];
        if (base + 3 < N) v3 = hist[base + 3];
    }
    if (PAD) { v0 = (v0+15)&~15; v1 = (v1+15)&~15; v2 = (v2+15)&~15; v3 = (v3+15)&~15; }
    const int s = v0 + v1 + v2 + v3;
    int incl = s;
#pragma unroll
    for (int off = 1; off < 64; off <<= 1) {
        int t = __shfl_up(incl, off, 64);
        if (lane >= off) incl += t;
    }
    if (lane == 63) wpart[wv] = incl;
    __syncthreads();
    int excl = coff[blockIdx.x] + incl - s;
    for (int w = 0; w < wv; ++w) excl += wpart[w];
    if (base + 0 < N) { rowptr[base + 0] = excl; cursor[base + 0] = excl; excl += v0; }
    if (base + 1 < N) { rowptr[base + 1] = excl; cursor[base + 1] = excl; excl += v1; }
    if (base + 2 < N) { rowptr[base + 2] = excl; cursor[base + 2] = excl; excl += v2; }
    if (base + 3 < N) { rowptr[base + 3] = excl; cursor[base + 3] = excl; excl += v3; }
}

// XCD-bucketed scatter, 16 dst-buckets in 2 temporal phases.
// Phase p (blocks [p*half, (p+1)*half)) handles buckets p*8 + (blockIdx&7);
// blockIdx&7 aligns with the %8 block->XCD round-robin, so at any instant one
// XCD holds ONE bucket's CSR write region: epC-slice (~1.18 MB) + epV-slice
// (~1.55 MB) ~= 2.7 MB < 4 MB L2/XCD. Partial 64B lines now combine to full
// lines before eviction (at 8 buckets the 5.45 MB region thrashed: WRITE_SIZE
// showed ~0.9 evictions per 8B write). Edge streams use nontemporal loads so
// the 19.2 MB/pass scan doesn't evict the write-region lines. Locality
// heuristic only; correctness holds under any block->XCD mapping: buckets are
// disjoint and each edge is written exactly once per direction.
__global__ __launch_bounds__(256) void scatter2_kernel(
        const int* __restrict__ ci, const int* __restrict__ vi,
        const float* __restrict__ ef,
        int* __restrict__ curC, int* __restrict__ curV,
        int2* __restrict__ epC, int2* __restrict__ epV, int E) {
    const int half  = gridDim.x >> 1;
    const int phase = (int)blockIdx.x >= half;
    const int b     = (int)blockIdx.x - phase * half;      // block id within phase
    const int rep   = (b & 7) + (phase << 3);              // bucket 0..15
    const int stride = (half >> 3) * blockDim.x;
    int i = (b >> 3) * blockDim.x + threadIdx.x;
    for (; i < E; i += stride) {
        const int cd = __builtin_nontemporal_load(ci + i);
        const int vd = __builtin_nontemporal_load(vi + i);
        const int bC = (cd * 16) / NCON;
        const int bV = (vd * 16) / NVAR;
        const bool doC = (bC == rep);
        const bool doV = (bV == rep);
        if (doC | doV) {
            const float f = __builtin_nontemporal_load(ef + i);
            if (doC) {
                const int slot = atomicAdd(&curC[cd], 1);
                epC[slot] = make_int2(vd, __float_as_int(f));
            }
            if (doV) {
                const int slot = atomicAdd(&curV[vd], 1);
                epV[slot] = make_int2(cd, __float_as_int(f));
            }
        }
    }
}

// ---------------- fused node linear: RL segment + LL segment -> f16 ----------------

__global__ __launch_bounds__(256, 4) void lin2_kernel(
        const float* __restrict__ XR, const float* __restrict__ WR,
        const float* __restrict__ bR, _Float16* __restrict__ YR, int NR,
        const float* __restrict__ XL, const float* __restrict__ WL,
        _Float16* __restrict__ YL, int NL, int nbR) {
    __shared__ __align__(16) _Float16 xbuf[4][EMB];
    const int wv = threadIdx.x >> 6;
    const int lane = threadIdx.x & 63;
    const bool isR = (int)blockIdx.x < nbR;
    const float* X = isR ? XR : XL;
    _Float16* Y    = isR ? YR : YL;
    const int N    = isR ? NR : NL;
    const int b0   = isR ? 0 : nbR;
    const int nb   = isR ? nbR : (gridDim.x - nbR);
    half2_t wh[32];
    load_w_f16(isR ? WR : WL, EMB, lane, wh);
    const float bias = isR ? bR[lane] : 0.0f;
    const int nW = nb * 4;
    for (int n = ((int)blockIdx.x - b0) * 4 + wv; n < N; n += nW) {
        xbuf[wv][lane] = (_Float16)X[(size_t)n * EMB + lane];
        Y[(size_t)n * EMB + lane] = (_Float16)matvec_f16(xbuf[wv], wh, bias);
    }
}

// ---------------- edge stage: wave per node, abar accumulate, Wf once/node ----------------
// Key identity: sum_e relu(LN(h_e)) @ Wf^T = (sum_e relu(LN(h_e))) @ Wf^T  (matvec is linear).

__global__ __launch_bounds__(256, 4) void edge_abar_kernel(
        const int* __restrict__ rp16, const int* __restrict__ deg,
        const int2* __restrict__ ep,
        const _Float16* __restrict__ RL, const _Float16* __restrict__ LL,
        const float* __restrict__ We, const float* __restrict__ g1,
        const float* __restrict__ b1, const float* __restrict__ Wf,
        const float* __restrict__ bfp, _Float16* __restrict__ AGG, int Nr) {
    __shared__ __align__(16) _Float16 abuf[4][EMB];
    const int wv   = threadIdx.x >> 6;
    const int lane = threadIdx.x & 63;
    const int col  = lane & 15;
    const int quad = lane >> 4;
    const int kb   = quad * 8;

    half2_t weh[8], gkh[8], bkh[8];
#pragma unroll
    for (int j = 0; j < 4; ++j) {
        weh[j]     = half2_t{(_Float16)We[kb + 2*j],      (_Float16)We[kb + 2*j + 1]};
        weh[4 + j] = half2_t{(_Float16)We[kb + 32 + 2*j], (_Float16)We[kb + 32 + 2*j + 1]};
        gkh[j]     = half2_t{(_Float16)g1[kb + 2*j],      (_Float16)g1[kb + 2*j + 1]};
        gkh[4 + j] = half2_t{(_Float16)g1[kb + 32 + 2*j], (_Float16)g1[kb + 32 + 2*j + 1]};
        bkh[j]     = half2_t{(_Float16)b1[kb + 2*j],      (_Float16)b1[kb + 2*j + 1]};
        bkh[4 + j] = half2_t{(_Float16)b1[kb + 32 + 2*j], (_Float16)b1[kb + 32 + 2*j + 1]};
    }
    half2_t whF[32];
    load_w_f16(Wf, EMB, lane, whF);
    const float bfv = bfp[lane];

    const int nW = gridDim.x * 4;
    for (int n = blockIdx.x * 4 + wv; n < Nr; n += nW) {
        const int g0  = rp16[n] >> 4;
        const int g1e = rp16[n + 1] >> 4;
        const int dn  = deg[n];
        half2_t rl2[8];
        *(f16x8*)&rl2[0] = *(const f16x8*)(RL + (size_t)n * EMB + kb);
        *(f16x8*)&rl2[4] = *(const f16x8*)(RL + (size_t)n * EMB + kb + 32);
        float acc[16];
#pragma unroll
        for (int j = 0; j < 16; ++j) acc[j] = 0.0f;

        if (g0 < g1e) {
            // prefetch first group
            bool livN = col < dn;
            int2 p = ep[(g0 << 4) + col];
            int sN = livN ? p.x : 0;
            float fN = livN ? __int_as_float(p.y) : 0.0f;
            f16x8 llaN = *(const f16x8*)(LL + (size_t)sN * EMB + kb);
            f16x8 llbN = *(const f16x8*)(LL + (size_t)sN * EMB + kb + 32);

            for (int g = g0; g < g1e; ++g) {
                const bool liv = livN;
                const float f = fN;
                half2_t h2[8];
                *(f16x8*)&h2[0] = llaN;
                *(f16x8*)&h2[4] = llbN;
                if (g + 1 < g1e) {
                    const int cnt = dn - ((g + 1 - g0) << 4);
                    livN = col < cnt;
                    p = ep[((g + 1) << 4) + col];
                    const int s2 = livN ? p.x : 0;
                    fN = livN ? __int_as_float(p.y) : 0.0f;
                    llaN = *(const f16x8*)(LL + (size_t)s2 * EMB + kb);
                    llbN = *(const f16x8*)(LL + (size_t)s2 * EMB + kb + 32);
                }
                const _Float16 fh = (_Float16)f;
                const half2_t f2 = half2_t{fh, fh};
                const half2_t one2 = half2_t{(_Float16)1.0f, (_Float16)1.0f};
                float ps = 0.0f, pq = 0.0f;
#pragma unroll
                for (int j = 0; j < 8; ++j) {
                    h2[j] = (h2[j] + rl2[j]) + f2 * weh[j];
                    ps = dot2f(h2[j], one2, ps);
                    pq = dot2f(h2[j], h2[j], pq);
                }
                ps += __shfl_xor(ps, 16, 64); ps += __shfl_xor(ps, 32, 64);
                pq += __shfl_xor(pq, 16, 64); pq += __shfl_xor(pq, 32, 64);
                const float mean = ps * (1.0f / EMB);
                const float var  = pq * (1.0f / EMB) - mean * mean;
                const float rs   = rsqrtf(var + EPSLN);
                const _Float16 rsh = (_Float16)rs;
                const _Float16 mnh = (_Float16)mean;
                const half2_t rs2 = half2_t{rsh, rsh};
                const half2_t mn2 = half2_t{mnh, mnh};
                const half2_t z2  = half2_t{(_Float16)0.0f, (_Float16)0.0f};
                if (liv) {
#pragma unroll
                    for (int j = 0; j < 8; ++j) {
                        const half2_t sc = gkh[j] * rs2;
                        half2_t a = (h2[j] - mn2) * sc + bkh[j];
                        a = hmax2(a, z2);
                        acc[2*j]   += (float)a.x;
                        acc[2*j+1] += (float)a.y;
                    }
                }
            }
        }
        // reduce abar partials across the 16 cols of each quad
#pragma unroll
        for (int st = 1; st < 16; st <<= 1) {
#pragma unroll
            for (int j = 0; j < 16; ++j)
                acc[j] += __shfl_xor(acc[j], st, 64);
        }
        // lane's element of abar: acc[col] maps to k = (col<8) ? kb+col : kb+32+(col-8)
        abuf[wv][(col < 8) ? (kb + col) : (kb + 24 + col)] = (_Float16)acc[col];
        // agg = abar @ Wf^T + deg*bf   (one matvec per node)
        AGG[(size_t)n * EMB + lane] = (_Float16)matvec_f16(abuf[wv], whF, (float)dn * bfv);
    }
}

// ---------------- fallback edge path (wave per node, dot2, f16 RL/LL) ----------------

__global__ __launch_bounds__(256, 4) void edge_csr_kernel(
        const int* __restrict__ rowptr, const int2* __restrict__ ep,
        const _Float16* __restrict__ RL, const _Float16* __restrict__ LL,
        const float* __restrict__ Wecol, const float* __restrict__ g1,
        const float* __restrict__ b1,
        const float* __restrict__ Wf, const float* __restrict__ bfp,
        _Float16* __restrict__ AGG, int Nr) {
    __shared__ __align__(16) _Float16 hbuf[4][EMB];
    const int wv = threadIdx.x >> 6;
    const int lane = threadIdx.x & 63;
    half2_t wh[32];
    load_w_f16(Wf, EMB, lane, wh);
    const float we  = Wecol[lane];
    const float g   = g1[lane];
    const float bb  = b1[lane];
    const float bf_ = bfp[lane];
    const int nW = gridDim.x * 4;
    for (int n = blockIdx.x * 4 + wv; n < Nr; n += nW) {
        const int beg = rowptr[n];
        const int end = rowptr[n + 1];
        const float rl = (float)RL[(size_t)n * EMB + lane];
        float acc = 0.0f;
        for (int idx = beg; idx < end; ++idx) {
            const int2 p = ep[idx];
            const float f = __int_as_float(p.y);
            float h = rl + (float)LL[(size_t)p.x * EMB + lane] + f * we;
            const float s1 = wtotal64(h);
            const float s2 = wtotal64(h * h);
            const float m   = s1 * (1.0f / EMB);
            const float var = s2 * (1.0f / EMB) - m * m;
            float hn = fmaxf((h - m) * rsqrtf(var + EPSLN) * g + bb, 0.0f);
            hbuf[wv][lane] = (_Float16)hn;
            acc = matvec_f16(hbuf[wv], wh, acc);
        }
        AGG[(size_t)n * EMB + lane] = (_Float16)(acc + (float)(end - beg) * bf_);
    }
}

// ---------------- fused output MLP ----------------
// z = LN(AGG); o = relu(Wo1a@z + Wo1b@right + bo1); right += Wo2@o + bo2

__global__ __launch_bounds__(256, 3) void out_kernel(
        const _Float16* __restrict__ AGG, float* __restrict__ right,
        const float* __restrict__ g2, const float* __restrict__ b2,
        const float* __restrict__ Wo1, const float* __restrict__ Wo2,
        const float* __restrict__ bo1, const float* __restrict__ bo2, int N) {
    __shared__ __align__(16) _Float16 zbuf[4][EMB];
    __shared__ __align__(16) _Float16 rbuf[4][EMB];
    __shared__ __align__(16) _Float16 obuf[4][EMB];
    const int wv = threadIdx.x >> 6;
    const int lane = threadIdx.x & 63;
    half2_t wh1[32], whB[32], wh2[32];
    load_w_f16(Wo1, 2 * EMB, lane, wh1);            // Wo1[:, 0:64]
    load_w_f16(Wo1 + EMB, 2 * EMB, lane, whB);      // Wo1[:, 64:128]
    load_w_f16(Wo2, EMB, lane, wh2);
    const float g    = g2[lane];
    const float bb   = b2[lane];
    const float bo1v = bo1[lane];
    const float bo2v = bo2[lane];
    const int nW = gridDim.x * 4;
    for (int n = blockIdx.x * 4 + wv; n < N; n += nW) {
        const float a = (float)AGG[(size_t)n * EMB + lane];
        const float rf = right[(size_t)n * EMB + lane];
        const float s1 = wtotal64(a);
        const float s2 = wtotal64(a * a);
        const float m   = s1 * (1.0f / EMB);
        const float var = s2 * (1.0f / EMB) - m * m;
        const float z = (a - m) * rsqrtf(var + EPSLN) * g + bb;
        zbuf[wv][lane] = (_Float16)z;
        rbuf[wv][lane] = (_Float16)rf;
        float acc = matvec_f16(zbuf[wv], wh1, bo1v);
        acc = matvec_f16(rbuf[wv], whB, acc);
        obuf[wv][lane] = (_Float16)fmaxf(acc, 0.0f);
        float acc2 = matvec_f16(obuf[wv], wh2, bo2v);
        right[(size_t)n * EMB + lane] = rf + acc2;
    }
}

extern "C" void kernel_launch(void* const* d_in, const int* in_sizes, int n_in,
                              void* d_out, int out_size, void* d_ws, size_t ws_size,
                              hipStream_t stream) {
    const float* cf  = (const float*)d_in[0];
    const float* vfp = (const float*)d_in[1];
    const int*   ei  = (const int*)d_in[2];
    const float* ef  = (const float*)d_in[3];
    const float* Wl  = (const float*)d_in[4];
    const float* bl  = (const float*)d_in[5];
    const float* We  = (const float*)d_in[6];
    const float* Wr  = (const float*)d_in[7];
    const float* g1  = (const float*)d_in[8];
    const float* b1  = (const float*)d_in[9];
    const float* Wf  = (const float*)d_in[10];
    const float* bfp = (const float*)d_in[11];
    const float* g2  = (const float*)d_in[12];
    const float* b2  = (const float*)d_in[13];
    const float* Wo1 = (const float*)d_in[14];
    const float* bo1 = (const float*)d_in[15];
    const float* Wo2 = (const float*)d_in[16];
    const float* bo2 = (const float*)d_in[17];

    float* c = (float*)d_out;
    float* v = c + (size_t)NCON * EMB;
    (void)hipMemcpyAsync(c, cf,  (size_t)NCON * EMB * sizeof(float), hipMemcpyDeviceToDevice, stream);
    (void)hipMemcpyAsync(v, vfp, (size_t)NVAR * EMB * sizeof(float), hipMemcpyDeviceToDevice, stream);

    float* wsf = (float*)d_ws;
    size_t off = 0;
    _Float16* AGG = (_Float16*)(wsf + off); off += (size_t)NVAR * EMB / 2;  // f16
    _Float16* RL  = (_Float16*)(wsf + off); off += (size_t)NVAR * EMB / 2;  // f16
    _Float16* LL  = (_Float16*)(wsf + off); off += (size_t)NVAR * EMB / 2;  // f16
    int* degC  = (int*)(wsf + off); off += NCON;
    int* degV  = (int*)(wsf + off); off += NVAR;
    int* rp16C = (int*)(wsf + off); off += NCON + 4;
    int* curC  = (int*)(wsf + off); off += NCON;
    int* rp16V = (int*)(wsf + off); off += NVAR + 4;
    int* curV  = (int*)(wsf + off); off += NVAR;
    int* csumC = (int*)(wsf + off); off += 128;
    int* coffC = (int*)(wsf + off); off += 128;
    int* csumV = (int*)(wsf + off); off += 128;
    int* coffV = (int*)(wsf + off); off += 128;
    size_t off_edges = off;
    int2* epC = (int2*)(wsf + off); off += (size_t)2 * PADEC;
    int2* epV = (int2*)(wsf + off); off += (size_t)2 * PADEV;
    const bool use_mfma = ws_size >= off * sizeof(float);
    if (!use_mfma) {
        off = off_edges;
        epC = (int2*)(wsf + off); off += (size_t)2 * NEDGE;
        epV = (int2*)(wsf + off); off += (size_t)2 * NEDGE;
    }

    const int* ci = ei;
    const int* vi = ei + NEDGE;

    const dim3 blk(256);
    const int NB = 2048;
    const int NBL = 1536;
    const int nchC = (NCON + 1023) / 1024;   // 49
    const int nchV = (NVAR + 1023) / 1024;   // 98

    (void)hipMemsetAsync(degC, 0, NCON * sizeof(int), stream);
    (void)hipMemsetAsync(degV, 0, NVAR * sizeof(int), stream);
    hist2_kernel<<<1024, blk, 0, stream>>>(ci, vi, degC, degV, NEDGE);
    if (use_mfma) {
        chunk_sum_kernel<true><<<nchC, blk, 0, stream>>>(degC, csumC, NCON);
        chunk_sum_kernel<true><<<nchV, blk, 0, stream>>>(degV, csumV, NVAR);
        chunk_offsets_kernel<<<1, 64, 0, stream>>>(csumC, coffC, rp16C, nchC, NCON);
        chunk_offsets_kernel<<<1, 64, 0, stream>>>(csumV, coffV, rp16V, nchV, NVAR);
        chunk_apply_kernel<true><<<nchC, blk, 0, stream>>>(degC, coffC, rp16C, curC, NCON);
        chunk_apply_kernel<true><<<nchV, blk, 0, stream>>>(degV, coffV, rp16V, curV, NVAR);
    } else {
        chunk_sum_kernel<false><<<nchC, blk, 0, stream>>>(degC, csumC, NCON);
        chunk_sum_kernel<false><<<nchV, blk, 0, stream>>>(degV, csumV, NVAR);
        chunk_offsets_kernel<<<1, 64, 0, stream>>>(csumC, coffC, rp16C, nchC, NCON);
        chunk_offsets_kernel<<<1, 64, 0, stream>>>(csumV, coffV, rp16V, nchV, NVAR);
        chunk_apply_kernel<false><<<nchC, blk, 0, stream>>>(degC, coffC, rp16C, curC, NCON);
        chunk_apply_kernel<false><<<nchV, blk, 0, stream>>>(degV, coffV, rp16V, curV, NVAR);
    }
    // 16 buckets, 2 temporal phases in one 4096-block launch: blocks 0..2047
    // handle buckets 0..7, blocks 2048..4095 handle buckets 8..15 (phase-1
    // blocks dispatch as phase-0 retires, so each XCD's L2 holds ~1 bucket
    // region ~2.7 MB at a time -> write combining).
    scatter2_kernel<<<4096, blk, 0, stream>>>(ci, vi, ef, curC, curV, epC, epV, NEDGE);

    for (int k = 0; k < 4; ++k) {
        const bool v2c = ((k & 1) == 0);
        float* right   = v2c ? c : v;
        float* left    = v2c ? v : c;
        const int Nr   = v2c ? NCON : NVAR;
        const int Nl   = v2c ? NVAR : NCON;
        const int nbR  = v2c ? NBL / 3 : 2 * NBL / 3;   // split blocks ~ Nr : Nl

        lin2_kernel<<<NBL, blk, 0, stream>>>(
            right, Wl + (size_t)k * EMB * EMB, bl + (size_t)k * EMB, RL, Nr,
            left,  Wr + (size_t)k * EMB * EMB, LL, Nl, nbR);

        if (use_mfma) {
            edge_abar_kernel<<<NB, blk, 0, stream>>>(
                v2c ? rp16C : rp16V, v2c ? degC : degV, v2c ? epC : epV,
                RL, LL, We + (size_t)k * EMB,
                g1 + (size_t)k * EMB, b1 + (size_t)k * EMB,
                Wf + (size_t)k * EMB * EMB, bfp + (size_t)k * EMB, AGG, Nr);
        } else {
            edge_csr_kernel<<<NB, blk, 0, stream>>>(
                v2c ? rp16C : rp16V, v2c ? epC : epV,
                RL, LL, We + (size_t)k * EMB,
                g1 + (size_t)k * EMB, b1 + (size_t)k * EMB,
                Wf + (size_t)k * EMB * EMB, bfp + (size_t)k * EMB, AGG, Nr);
        }
        out_kernel<<<NB, blk, 0, stream>>>(AGG, right,
                                           g2 + (size_t)k * EMB, b2 + (size_t)k * EMB,
                                           Wo1 + (size_t)k * EMB * 2 * EMB,
                                           Wo2 + (size_t)k * EMB * EMB,
                                           bo1 + (size_t)k * EMB, bo2 + (size_t)k * EMB,
                                           Nr);
    }
}

// Round 2
// 1213.944 us; speedup vs baseline: 1.0266x; 1.0266x over previous
//
#include <hip/hip_runtime.h>

#define EMB   64
#define NCON  50000
#define NVAR  100000
#define NEDGE 1600000
#define EPSLN 1e-5f

// padded-CSR capacities (worst case: every node pads +15)
#define PADEC (NEDGE + 15 * NCON)    // 2,350,000
#define PADEV (NEDGE + 15 * NVAR)    // 3,100,000

typedef _Float16 half2_t __attribute__((ext_vector_type(2)));
typedef _Float16 f16x8  __attribute__((ext_vector_type(8)));

// ---- wave-total via DPP (no DS ops) ----
template <int CTRL, int RMASK>
__device__ __forceinline__ float dpp_add_f(float x) {
    int m = __builtin_amdgcn_update_dpp(0, __builtin_bit_cast(int, x), CTRL, RMASK, 0xf, true);
    return x + __builtin_bit_cast(float, m);
}
__device__ __forceinline__ float wtotal64(float x) {
    x = dpp_add_f<0x111, 0xf>(x);
    x = dpp_add_f<0x112, 0xf>(x);
    x = dpp_add_f<0x114, 0xf>(x);
    x = dpp_add_f<0x118, 0xf>(x);
    x = dpp_add_f<0x142, 0xa>(x);
    x = dpp_add_f<0x143, 0xc>(x);
    return __builtin_bit_cast(float, __builtin_amdgcn_readlane(__builtin_bit_cast(int, x), 63));
}
template <int CTRL, int RMASK>
__device__ __forceinline__ int dpp_add_i(int x) {
    return x + __builtin_amdgcn_update_dpp(0, x, CTRL, RMASK, 0xf, true);
}
__device__ __forceinline__ int wtotal64_i(int x) {
    x = dpp_add_i<0x111, 0xf>(x);
    x = dpp_add_i<0x112, 0xf>(x);
    x = dpp_add_i<0x114, 0xf>(x);
    x = dpp_add_i<0x118, 0xf>(x);
    x = dpp_add_i<0x142, 0xa>(x);
    x = dpp_add_i<0x143, 0xc>(x);
    return __builtin_amdgcn_readlane(x, 63);
}

__device__ __forceinline__ float dot2f(half2_t a, half2_t b, float c) {
    return __builtin_amdgcn_fdot2(a, b, c, false);
}

__device__ __forceinline__ half2_t hmax2(half2_t a, half2_t b) {
#if defined(__has_builtin) && __has_builtin(__builtin_elementwise_max)
    return __builtin_elementwise_max(a, b);
#else
    half2_t r;
    r.x = a.x > b.x ? a.x : b.x;
    r.y = a.y > b.y ? a.y : b.y;
    return r;
#endif
}

// 8 x ds_read_b128 + 32 x v_dot2 with 4 independent accumulator chains
__device__ __forceinline__ float matvec_f16(const _Float16* __restrict__ buf,
                                            const half2_t* __restrict__ wh, float acc) {
    const float4* hp4 = (const float4*)buf;
    float a0 = acc, a1 = 0.0f, a2 = 0.0f, a3 = 0.0f;
#pragma unroll
    for (int j4 = 0; j4 < 8; ++j4) {
        float4 t = hp4[j4];
        a0 = dot2f(wh[4 * j4 + 0], __builtin_bit_cast(half2_t, t.x), a0);
        a1 = dot2f(wh[4 * j4 + 1], __builtin_bit_cast(half2_t, t.y), a1);
        a2 = dot2f(wh[4 * j4 + 2], __builtin_bit_cast(half2_t, t.z), a2);
        a3 = dot2f(wh[4 * j4 + 3], __builtin_bit_cast(half2_t, t.w), a3);
    }
    return (a0 + a1) + (a2 + a3);
}

__device__ __forceinline__ void load_w_f16(const float* __restrict__ W, int stride,
                                           int lane, half2_t* wh) {
#pragma unroll
    for (int j4 = 0; j4 < 16; ++j4) {
        float4 t = *(const float4*)(W + (size_t)lane * stride + j4 * 4);
        wh[2 * j4 + 0] = half2_t{(_Float16)t.x, (_Float16)t.y};
        wh[2 * j4 + 1] = half2_t{(_Float16)t.z, (_Float16)t.w};
    }
}

// ---------------- CSR build ----------------

// both directions in one pass (plain loads: the edge stream should L3-cache —
// round-1 showed nontemporal hints double HBM FETCH by defeating that)
__global__ __launch_bounds__(256) void hist2_kernel(
        const int* __restrict__ ci, const int* __restrict__ vi,
        int* __restrict__ degC, int* __restrict__ degV, int E) {
    int i = blockIdx.x * blockDim.x + threadIdx.x;
    for (; i < E; i += gridDim.x * blockDim.x) {
        atomicAdd(&degC[ci[i]], 1);
        atomicAdd(&degV[vi[i]], 1);
    }
}

template <bool PAD>
__global__ __launch_bounds__(256) void chunk_sum_kernel(const int* __restrict__ hist,
                                                        int* __restrict__ csum, int N) {
    __shared__ int wpart[4];
    const int base = blockIdx.x * 1024 + threadIdx.x * 4;
    int s = 0;
    if (base + 3 < N) {
        int4 t = *(const int4*)(hist + base);
        if (PAD) s = ((t.x+15)&~15) + ((t.y+15)&~15) + ((t.z+15)&~15) + ((t.w+15)&~15);
        else     s = t.x + t.y + t.z + t.w;
    } else {
#pragma unroll
        for (int j = 0; j < 4; ++j)
            if (base + j < N) { int v = hist[base + j]; s += PAD ? ((v+15)&~15) : v; }
    }
    s = wtotal64_i(s);
    if ((threadIdx.x & 63) == 0) wpart[threadIdx.x >> 6] = s;
    __syncthreads();
    if (threadIdx.x == 0) csum[blockIdx.x] = wpart[0] + wpart[1] + wpart[2] + wpart[3];
}

__global__ void chunk_offsets_kernel(const int* __restrict__ csum, int* __restrict__ coff,
                                     int* __restrict__ rowptr, int nchunk, int N) {
    const int lane = threadIdx.x;
    int carry = 0;
    for (int base = 0; base < nchunk; base += 64) {
        const int i = base + lane;
        int val = (i < nchunk) ? csum[i] : 0;
        int incl = val;
#pragma unroll
        for (int off = 1; off < 64; off <<= 1) {
            int t = __shfl_up(incl, off, 64);
            if (lane >= off) incl += t;
        }
        if (i < nchunk) coff[i] = incl - val + carry;
        carry += __shfl(incl, 63, 64);
    }
    if (lane == 0) rowptr[N] = carry;
}

template <bool PAD>
__global__ __launch_bounds__(256) void chunk_apply_kernel(
        const int* __restrict__ hist, const int* __restrict__ coff,
        int* __restrict__ rowptr, int* __restrict__ cursor, int N) {
    __shared__ int wpart[4];
    const int wv = threadIdx.x >> 6;
    const int lane = threadIdx.x & 63;
    const int base = blockIdx.x * 1024 + threadIdx.x * 4;
    int v0 = 0, v1 = 0, v2 = 0, v3 = 0;
    if (base + 3 < N) {
        int4 t = *(const int4*)(hist + base);
        v0 = t.x; v1 = t.y; v2 = t.z; v3 = t.w;
    } else {
        if (base + 0 < N) v0 = hist[base + 0];
        if (base + 1 < N) v1 = hist[base + 1];
        if (base + 2 < N) v2 = hist[base + 2];
        if (base + 3 < N) v3 = hist[base + 3];
    }
    if (PAD) { v0 = (v0+15)&~15; v1 = (v1+15)&~15; v2 = (v2+15)&~15; v3 = (v3+15)&~15; }
    const int s = v0 + v1 + v2 + v3;
    int incl = s;
#pragma unroll
    for (int off = 1; off < 64; off <<= 1) {
        int t = __shfl_up(incl, off, 64);
        if (lane >= off) incl += t;
    }
    if (lane == 63) wpart[wv] = incl;
    __syncthreads();
    int excl = coff[blockIdx.x] + incl - s;
    for (int w = 0; w < wv; ++w) excl += wpart[w];
    if (base + 0 < N) { rowptr[base + 0] = excl; cursor[base + 0] = excl; excl += v0; }
    if (base + 1 < N) { rowptr[base + 1] = excl; cursor[base + 1] = excl; excl += v1; }
    if (base + 2 < N) { rowptr[base + 2] = excl; cursor[base + 2] = excl; excl += v2; }
    if (base + 3 < N) { rowptr[base + 3] = excl; cursor[base + 3] = excl; excl += v3; }
}

// XCD-bucketed scatter, ONE direction per launch. 8 dst-buckets; bucket =
// blockIdx&7 aligns with the %8 block->XCD round-robin, so each XCD's L2
// holds exactly one bucket's CSR write region: epC/8 ~= 2.35 MB or epV/8 ~=
// 3.1 MB, both < 4 MB L2/XCD. Round-1 lesson: phases inside ONE launch
// overlap (blocks retire gradually) and both regions co-occupy the L2 -> no
// combining; separate launches are the only hard temporal barrier. Edge
// stream uses plain loads so the first scan L3-caches it and the other 7
// scans (and the 2nd launch) are L3 hits. src/ef loaded only on bucket match.
// Locality heuristic only; correctness holds under any block->XCD mapping:
// buckets are disjoint and each edge is written exactly once per launch.
template <int NDST>
__global__ __launch_bounds__(256) void scatter_dir_kernel(
        const int* __restrict__ dst, const int* __restrict__ src,
        const float* __restrict__ ef,
        int* __restrict__ cur, int2* __restrict__ ep, int E) {
    const int rep = blockIdx.x & 7;
    const int stride = (gridDim.x >> 3) * blockDim.x;
    int i = (blockIdx.x >> 3) * blockDim.x + threadIdx.x;
    for (; i < E; i += stride) {
        const int d = dst[i];
        const int b = (int)(((long long)d * 8) / NDST);
        if (b == rep) {
            const int slot = atomicAdd(&cur[d], 1);
            ep[slot] = make_int2(src[i], __float_as_int(ef[i]));
        }
    }
}

// ---------------- fused node linear: RL segment + LL segment -> f16 ----------------

__global__ __launch_bounds__(256, 4) void lin2_kernel(
        const float* __restrict__ XR, const float* __restrict__ WR,
        const float* __restrict__ bR, _Float16* __restrict__ YR, int NR,
        const float* __restrict__ XL, const float* __restrict__ WL,
        _Float16* __restrict__ YL, int NL, int nbR) {
    __shared__ __align__(16) _Float16 xbuf[4][EMB];
    const int wv = threadIdx.x >> 6;
    const int lane = threadIdx.x & 63;
    const bool isR = (int)blockIdx.x < nbR;
    const float* X = isR ? XR : XL;
    _Float16* Y    = isR ? YR : YL;
    const int N    = isR ? NR : NL;
    const int b0   = isR ? 0 : nbR;
    const int nb   = isR ? nbR : (gridDim.x - nbR);
    half2_t wh[32];
    load_w_f16(isR ? WR : WL, EMB, lane, wh);
    const float bias = isR ? bR[lane] : 0.0f;
    const int nW = nb * 4;
    for (int n = ((int)blockIdx.x - b0) * 4 + wv; n < N; n += nW) {
        xbuf[wv][lane] = (_Float16)X[(size_t)n * EMB + lane];
        Y[(size_t)n * EMB + lane] = (_Float16)matvec_f16(xbuf[wv], wh, bias);
    }
}

// ---------------- edge stage: wave per node, abar accumulate, Wf once/node ----------------
// Key identity: sum_e relu(LN(h_e)) @ Wf^T = (sum_e relu(LN(h_e))) @ Wf^T  (matvec is linear).

__global__ __launch_bounds__(256, 4) void edge_abar_kernel(
        const int* __restrict__ rp16, const int* __restrict__ deg,
        const int2* __restrict__ ep,
        const _Float16* __restrict__ RL, const _Float16* __restrict__ LL,
        const float* __restrict__ We, const float* __restrict__ g1,
        const float* __restrict__ b1, const float* __restrict__ Wf,
        const float* __restrict__ bfp, _Float16* __restrict__ AGG, int Nr) {
    __shared__ __align__(16) _Float16 abuf[4][EMB];
    const int wv   = threadIdx.x >> 6;
    const int lane = threadIdx.x & 63;
    const int col  = lane & 15;
    const int quad = lane >> 4;
    const int kb   = quad * 8;

    half2_t weh[8], gkh[8], bkh[8];
#pragma unroll
    for (int j = 0; j < 4; ++j) {
        weh[j]     = half2_t{(_Float16)We[kb + 2*j],      (_Float16)We[kb + 2*j + 1]};
        weh[4 + j] = half2_t{(_Float16)We[kb + 32 + 2*j], (_Float16)We[kb + 32 + 2*j + 1]};
        gkh[j]     = half2_t{(_Float16)g1[kb + 2*j],      (_Float16)g1[kb + 2*j + 1]};
        gkh[4 + j] = half2_t{(_Float16)g1[kb + 32 + 2*j], (_Float16)g1[kb + 32 + 2*j + 1]};
        bkh[j]     = half2_t{(_Float16)b1[kb + 2*j],      (_Float16)b1[kb + 2*j + 1]};
        bkh[4 + j] = half2_t{(_Float16)b1[kb + 32 + 2*j], (_Float16)b1[kb + 32 + 2*j + 1]};
    }
    half2_t whF[32];
    load_w_f16(Wf, EMB, lane, whF);
    const float bfv = bfp[lane];

    const int nW = gridDim.x * 4;
    for (int n = blockIdx.x * 4 + wv; n < Nr; n += nW) {
        const int g0  = rp16[n] >> 4;
        const int g1e = rp16[n + 1] >> 4;
        const int dn  = deg[n];
        half2_t rl2[8];
        *(f16x8*)&rl2[0] = *(const f16x8*)(RL + (size_t)n * EMB + kb);
        *(f16x8*)&rl2[4] = *(const f16x8*)(RL + (size_t)n * EMB + kb + 32);
        float acc[16];
#pragma unroll
        for (int j = 0; j < 16; ++j) acc[j] = 0.0f;

        if (g0 < g1e) {
            // prefetch first group
            bool livN = col < dn;
            int2 p = ep[(g0 << 4) + col];
            int sN = livN ? p.x : 0;
            float fN = livN ? __int_as_float(p.y) : 0.0f;
            f16x8 llaN = *(const f16x8*)(LL + (size_t)sN * EMB + kb);
            f16x8 llbN = *(const f16x8*)(LL + (size_t)sN * EMB + kb + 32);

            for (int g = g0; g < g1e; ++g) {
                const bool liv = livN;
                const float f = fN;
                half2_t h2[8];
                *(f16x8*)&h2[0] = llaN;
                *(f16x8*)&h2[4] = llbN;
                if (g + 1 < g1e) {
                    const int cnt = dn - ((g + 1 - g0) << 4);
                    livN = col < cnt;
                    p = ep[((g + 1) << 4) + col];
                    const int s2 = livN ? p.x : 0;
                    fN = livN ? __int_as_float(p.y) : 0.0f;
                    llaN = *(const f16x8*)(LL + (size_t)s2 * EMB + kb);
                    llbN = *(const f16x8*)(LL + (size_t)s2 * EMB + kb + 32);
                }
                const _Float16 fh = (_Float16)f;
                const half2_t f2 = half2_t{fh, fh};
                const half2_t one2 = half2_t{(_Float16)1.0f, (_Float16)1.0f};
                float ps = 0.0f, pq = 0.0f;
#pragma unroll
                for (int j = 0; j < 8; ++j) {
                    h2[j] = (h2[j] + rl2[j]) + f2 * weh[j];
                    ps = dot2f(h2[j], one2, ps);
                    pq = dot2f(h2[j], h2[j], pq);
                }
                ps += __shfl_xor(ps, 16, 64); ps += __shfl_xor(ps, 32, 64);
                pq += __shfl_xor(pq, 16, 64); pq += __shfl_xor(pq, 32, 64);
                const float mean = ps * (1.0f / EMB);
                const float var  = pq * (1.0f / EMB) - mean * mean;
                const float rs   = rsqrtf(var + EPSLN);
                const _Float16 rsh = (_Float16)rs;
                const _Float16 mnh = (_Float16)mean;
                const half2_t rs2 = half2_t{rsh, rsh};
                const half2_t mn2 = half2_t{mnh, mnh};
                const half2_t z2  = half2_t{(_Float16)0.0f, (_Float16)0.0f};
                if (liv) {
#pragma unroll
                    for (int j = 0; j < 8; ++j) {
                        const half2_t sc = gkh[j] * rs2;
                        half2_t a = (h2[j] - mn2) * sc + bkh[j];
                        a = hmax2(a, z2);
                        acc[2*j]   += (float)a.x;
                        acc[2*j+1] += (float)a.y;
                    }
                }
            }
        }
        // reduce abar partials across the 16 cols of each quad
#pragma unroll
        for (int st = 1; st < 16; st <<= 1) {
#pragma unroll
            for (int j = 0; j < 16; ++j)
                acc[j] += __shfl_xor(acc[j], st, 64);
        }
        // lane's element of abar: acc[col] maps to k = (col<8) ? kb+col : kb+32+(col-8)
        abuf[wv][(col < 8) ? (kb + col) : (kb + 24 + col)] = (_Float16)acc[col];
        // agg = abar @ Wf^T + deg*bf   (one matvec per node)
        AGG[(size_t)n * EMB + lane] = (_Float16)matvec_f16(abuf[wv], whF, (float)dn * bfv);
    }
}

// ---------------- fallback edge path (wave per node, dot2, f16 RL/LL) ----------------

__global__ __launch_bounds__(256, 4) void edge_csr_kernel(
        const int* __restrict__ rowptr, const int2* __restrict__ ep,
        const _Float16* __restrict__ RL, const _Float16* __restrict__ LL,
        const float* __restrict__ Wecol, const float* __restrict__ g1,
        const float* __restrict__ b1,
        const float* __restrict__ Wf, const float* __restrict__ bfp,
        _Float16* __restrict__ AGG, int Nr) {
    __shared__ __align__(16) _Float16 hbuf[4][EMB];
    const int wv = threadIdx.x >> 6;
    const int lane = threadIdx.x & 63;
    half2_t wh[32];
    load_w_f16(Wf, EMB, lane, wh);
    const float we  = Wecol[lane];
    const float g   = g1[lane];
    const float bb  = b1[lane];
    const float bf_ = bfp[lane];
    const int nW = gridDim.x * 4;
    for (int n = blockIdx.x * 4 + wv; n < Nr; n += nW) {
        const int beg = rowptr[n];
        const int end = rowptr[n + 1];
        const float rl = (float)RL[(size_t)n * EMB + lane];
        float acc = 0.0f;
        for (int idx = beg; idx < end; ++idx) {
            const int2 p = ep[idx];
            const float f = __int_as_float(p.y);
            float h = rl + (float)LL[(size_t)p.x * EMB + lane] + f * we;
            const float s1 = wtotal64(h);
            const float s2 = wtotal64(h * h);
            const float m   = s1 * (1.0f / EMB);
            const float var = s2 * (1.0f / EMB) - m * m;
            float hn = fmaxf((h - m) * rsqrtf(var + EPSLN) * g + bb, 0.0f);
            hbuf[wv][lane] = (_Float16)hn;
            acc = matvec_f16(hbuf[wv], wh, acc);
        }
        AGG[(size_t)n * EMB + lane] = (_Float16)(acc + (float)(end - beg) * bf_);
    }
}

// ---------------- fused output MLP ----------------
// z = LN(AGG); o = relu(Wo1a@z + Wo1b@right + bo1); right += Wo2@o + bo2

__global__ __launch_bounds__(256, 3) void out_kernel(
        const _Float16* __restrict__ AGG, float* __restrict__ right,
        const float* __restrict__ g2, const float* __restrict__ b2,
        const float* __restrict__ Wo1, const float* __restrict__ Wo2,
        const float* __restrict__ bo1, const float* __restrict__ bo2, int N) {
    __shared__ __align__(16) _Float16 zbuf[4][EMB];
    __shared__ __align__(16) _Float16 rbuf[4][EMB];
    __shared__ __align__(16) _Float16 obuf[4][EMB];
    const int wv = threadIdx.x >> 6;
    const int lane = threadIdx.x & 63;
    half2_t wh1[32], whB[32], wh2[32];
    load_w_f16(Wo1, 2 * EMB, lane, wh1);            // Wo1[:, 0:64]
    load_w_f16(Wo1 + EMB, 2 * EMB, lane, whB);      // Wo1[:, 64:128]
    load_w_f16(Wo2, EMB, lane, wh2);
    const float g    = g2[lane];
    const float bb   = b2[lane];
    const float bo1v = bo1[lane];
    const float bo2v = bo2[lane];
    const int nW = gridDim.x * 4;
    for (int n = blockIdx.x * 4 + wv; n < N; n += nW) {
        const float a = (float)AGG[(size_t)n * EMB + lane];
        const float rf = right[(size_t)n * EMB + lane];
        const float s1 = wtotal64(a);
        const float s2 = wtotal64(a * a);
        const float m   = s1 * (1.0f / EMB);
        const float var = s2 * (1.0f / EMB) - m * m;
        const float z = (a - m) * rsqrtf(var + EPSLN) * g + bb;
        zbuf[wv][lane] = (_Float16)z;
        rbuf[wv][lane] = (_Float16)rf;
        float acc = matvec_f16(zbuf[wv], wh1, bo1v);
        acc = matvec_f16(rbuf[wv], whB, acc);
        obuf[wv][lane] = (_Float16)fmaxf(acc, 0.0f);
        float acc2 = matvec_f16(obuf[wv], wh2, bo2v);
        right[(size_t)n * EMB + lane] = rf + acc2;
    }
}

extern "C" void kernel_launch(void* const* d_in, const int* in_sizes, int n_in,
                              void* d_out, int out_size, void* d_ws, size_t ws_size,
                              hipStream_t stream) {
    const float* cf  = (const float*)d_in[0];
    const float* vfp = (const float*)d_in[1];
    const int*   ei  = (const int*)d_in[2];
    const float* ef  = (const float*)d_in[3];
    const float* Wl  = (const float*)d_in[4];
    const float* bl  = (const float*)d_in[5];
    const float* We  = (const float*)d_in[6];
    const float* Wr  = (const float*)d_in[7];
    const float* g1  = (const float*)d_in[8];
    const float* b1  = (const float*)d_in[9];
    const float* Wf  = (const float*)d_in[10];
    const float* bfp = (const float*)d_in[11];
    const float* g2  = (const float*)d_in[12];
    const float* b2  = (const float*)d_in[13];
    const float* Wo1 = (const float*)d_in[14];
    const float* bo1 = (const float*)d_in[15];
    const float* Wo2 = (const float*)d_in[16];
    const float* bo2 = (const float*)d_in[17];

    float* c = (float*)d_out;
    float* v = c + (size_t)NCON * EMB;
    (void)hipMemcpyAsync(c, cf,  (size_t)NCON * EMB * sizeof(float), hipMemcpyDeviceToDevice, stream);
    (void)hipMemcpyAsync(v, vfp, (size_t)NVAR * EMB * sizeof(float), hipMemcpyDeviceToDevice, stream);

    float* wsf = (float*)d_ws;
    size_t off = 0;
    _Float16* AGG = (_Float16*)(wsf + off); off += (size_t)NVAR * EMB / 2;  // f16
    _Float16* RL  = (_Float16*)(wsf + off); off += (size_t)NVAR * EMB / 2;  // f16
    _Float16* LL  = (_Float16*)(wsf + off); off += (size_t)NVAR * EMB / 2;  // f16
    int* degC  = (int*)(wsf + off); off += NCON;
    int* degV  = (int*)(wsf + off); off += NVAR;
    int* rp16C = (int*)(wsf + off); off += NCON + 4;
    int* curC  = (int*)(wsf + off); off += NCON;
    int* rp16V = (int*)(wsf + off); off += NVAR + 4;
    int* curV  = (int*)(wsf + off); off += NVAR;
    int* csumC = (int*)(wsf + off); off += 128;
    int* coffC = (int*)(wsf + off); off += 128;
    int* csumV = (int*)(wsf + off); off += 128;
    int* coffV = (int*)(wsf + off); off += 128;
    size_t off_edges = off;
    int2* epC = (int2*)(wsf + off); off += (size_t)2 * PADEC;
    int2* epV = (int2*)(wsf + off); off += (size_t)2 * PADEV;
    const bool use_mfma = ws_size >= off * sizeof(float);
    if (!use_mfma) {
        off = off_edges;
        epC = (int2*)(wsf + off); off += (size_t)2 * NEDGE;
        epV = (int2*)(wsf + off); off += (size_t)2 * NEDGE;
    }

    const int* ci = ei;
    const int* vi = ei + NEDGE;

    const dim3 blk(256);
    const int NB = 2048;
    const int NBL = 1536;
    const int nchC = (NCON + 1023) / 1024;   // 49
    const int nchV = (NVAR + 1023) / 1024;   // 98

    (void)hipMemsetAsync(degC, 0, NCON * sizeof(int), stream);
    (void)hipMemsetAsync(degV, 0, NVAR * sizeof(int), stream);
    hist2_kernel<<<1024, blk, 0, stream>>>(ci, vi, degC, degV, NEDGE);
    if (use_mfma) {
        chunk_sum_kernel<true><<<nchC, blk, 0, stream>>>(degC, csumC, NCON);
        chunk_sum_kernel<true><<<nchV, blk, 0, stream>>>(degV, csumV, NVAR);
        chunk_offsets_kernel<<<1, 64, 0, stream>>>(csumC, coffC, rp16C, nchC, NCON);
        chunk_offsets_kernel<<<1, 64, 0, stream>>>(csumV, coffV, rp16V, nchV, NVAR);
        chunk_apply_kernel<true><<<nchC, blk, 0, stream>>>(degC, coffC, rp16C, curC, NCON);
        chunk_apply_kernel<true><<<nchV, blk, 0, stream>>>(degV, coffV, rp16V, curV, NVAR);
    } else {
        chunk_sum_kernel<false><<<nchC, blk, 0, stream>>>(degC, csumC, NCON);
        chunk_sum_kernel<false><<<nchV, blk, 0, stream>>>(degV, csumV, NVAR);
        chunk_offsets_kernel<<<1, 64, 0, stream>>>(csumC, coffC, rp16C, nchC, NCON);
        chunk_offsets_kernel<<<1, 64, 0, stream>>>(csumV, coffV, rp16V, nchV, NVAR);
        chunk_apply_kernel<false><<<nchC, blk, 0, stream>>>(degC, coffC, rp16C, curC, NCON);
        chunk_apply_kernel<false><<<nchV, blk, 0, stream>>>(degV, coffV, rp16V, curV, NVAR);
    }
    // one direction per launch: hard temporal separation so each XCD's L2
    // holds only that direction's bucket region (C: 2.35 MB, V: 3.1 MB).
    scatter_dir_kernel<NCON><<<2048, blk, 0, stream>>>(ci, vi, ef, curC, epC, NEDGE);
    scatter_dir_kernel<NVAR><<<2048, blk, 0, stream>>>(vi, ci, ef, curV, epV, NEDGE);

    for (int k = 0; k < 4; ++k) {
        const bool v2c = ((k & 1) == 0);
        float* right   = v2c ? c : v;
        float* left    = v2c ? v : c;
        const int Nr   = v2c ? NCON : NVAR;
        const int Nl   = v2c ? NVAR : NCON;
        const int nbR  = v2c ? NBL / 3 : 2 * NBL / 3;   // split blocks ~ Nr : Nl

        lin2_kernel<<<NBL, blk, 0, stream>>>(
            right, Wl + (size_t)k * EMB * EMB, bl + (size_t)k * EMB, RL, Nr,
            left,  Wr + (size_t)k * EMB * EMB, LL, Nl, nbR);

        if (use_mfma) {
            edge_abar_kernel<<<NB, blk, 0, stream>>>(
                v2c ? rp16C : rp16V, v2c ? degC : degV, v2c ? epC : epV,
                RL, LL, We + (size_t)k * EMB,
                g1 + (size_t)k * EMB, b1 + (size_t)k * EMB,
                Wf + (size_t)k * EMB * EMB, bfp + (size_t)k * EMB, AGG, Nr);
        } else {
            edge_csr_kernel<<<NB, blk, 0, stream>>>(
                v2c ? rp16C : rp16V, v2c ? epC : epV,
                RL, LL, We + (size_t)k * EMB,
                g1 + (size_t)k * EMB, b1 + (size_t)k * EMB,
                Wf + (size_t)k * EMB * EMB, bfp + (size_t)k * EMB, AGG, Nr);
        }
        out_kernel<<<NB, blk, 0, stream>>>(AGG, right,
                                           g2 + (size_t)k * EMB, b2 + (size_t)k * EMB,
                                           Wo1 + (size_t)k * EMB * 2 * EMB,
                                           Wo2 + (size_t)k * EMB * EMB,
                                           bo1 + (size_t)k * EMB, bo2 + (size_t)k * EMB,
                                           Nr);
    }
}

// Round 3
// 1179.521 us; speedup vs baseline: 1.0566x; 1.0292x over previous
//
#include <hip/hip_runtime.h>

#define EMB   64
#define NCON  50000
#define NVAR  100000
#define NEDGE 1600000
#define EPSLN 1e-5f

// padded-CSR capacities (worst case: every node pads +15)
#define PADEC (NEDGE + 15 * NCON)    // 2,350,000
#define PADEV (NEDGE + 15 * NVAR)    // 3,100,000

// LDS-chunked histogram: 12544 counters/chunk (50 KB LDS), C=4 chunks, V=8.
#define HCHUNK 12544
#define HSEG   32
#define HCHC   4
#define HCHV   8

typedef _Float16 half2_t __attribute__((ext_vector_type(2)));
typedef _Float16 f16x8  __attribute__((ext_vector_type(8)));

// ---- wave-total via DPP (no DS ops) ----
template <int CTRL, int RMASK>
__device__ __forceinline__ float dpp_add_f(float x) {
    int m = __builtin_amdgcn_update_dpp(0, __builtin_bit_cast(int, x), CTRL, RMASK, 0xf, true);
    return x + __builtin_bit_cast(float, m);
}
__device__ __forceinline__ float wtotal64(float x) {
    x = dpp_add_f<0x111, 0xf>(x);
    x = dpp_add_f<0x112, 0xf>(x);
    x = dpp_add_f<0x114, 0xf>(x);
    x = dpp_add_f<0x118, 0xf>(x);
    x = dpp_add_f<0x142, 0xa>(x);
    x = dpp_add_f<0x143, 0xc>(x);
    return __builtin_bit_cast(float, __builtin_amdgcn_readlane(__builtin_bit_cast(int, x), 63));
}
template <int CTRL, int RMASK>
__device__ __forceinline__ int dpp_add_i(int x) {
    return x + __builtin_amdgcn_update_dpp(0, x, CTRL, RMASK, 0xf, true);
}
__device__ __forceinline__ int wtotal64_i(int x) {
    x = dpp_add_i<0x111, 0xf>(x);
    x = dpp_add_i<0x112, 0xf>(x);
    x = dpp_add_i<0x114, 0xf>(x);
    x = dpp_add_i<0x118, 0xf>(x);
    x = dpp_add_i<0x142, 0xa>(x);
    x = dpp_add_i<0x143, 0xc>(x);
    return __builtin_amdgcn_readlane(x, 63);
}

__device__ __forceinline__ float dot2f(half2_t a, half2_t b, float c) {
    return __builtin_amdgcn_fdot2(a, b, c, false);
}

__device__ __forceinline__ half2_t hmax2(half2_t a, half2_t b) {
#if defined(__has_builtin) && __has_builtin(__builtin_elementwise_max)
    return __builtin_elementwise_max(a, b);
#else
    half2_t r;
    r.x = a.x > b.x ? a.x : b.x;
    r.y = a.y > b.y ? a.y : b.y;
    return r;
#endif
}

// 8 x ds_read_b128 + 32 x v_dot2 with 4 independent accumulator chains
__device__ __forceinline__ float matvec_f16(const _Float16* __restrict__ buf,
                                            const half2_t* __restrict__ wh, float acc) {
    const float4* hp4 = (const float4*)buf;
    float a0 = acc, a1 = 0.0f, a2 = 0.0f, a3 = 0.0f;
#pragma unroll
    for (int j4 = 0; j4 < 8; ++j4) {
        float4 t = hp4[j4];
        a0 = dot2f(wh[4 * j4 + 0], __builtin_bit_cast(half2_t, t.x), a0);
        a1 = dot2f(wh[4 * j4 + 1], __builtin_bit_cast(half2_t, t.y), a1);
        a2 = dot2f(wh[4 * j4 + 2], __builtin_bit_cast(half2_t, t.z), a2);
        a3 = dot2f(wh[4 * j4 + 3], __builtin_bit_cast(half2_t, t.w), a3);
    }
    return (a0 + a1) + (a2 + a3);
}

__device__ __forceinline__ void load_w_f16(const float* __restrict__ W, int stride,
                                           int lane, half2_t* wh) {
#pragma unroll
    for (int j4 = 0; j4 < 16; ++j4) {
        float4 t = *(const float4*)(W + (size_t)lane * stride + j4 * 4);
        wh[2 * j4 + 0] = half2_t{(_Float16)t.x, (_Float16)t.y};
        wh[2 * j4 + 1] = half2_t{(_Float16)t.z, (_Float16)t.w};
    }
}

// ---------------- CSR build ----------------

// LDS-chunked histogram, NO global atomics. Round-2 evidence: 3.2M device
// atomicAdds cost ~31B each of memory-side partial-sector writes (99.7 MB
// WRITE_SIZE, 129 us, atomic-transaction-bound at ~25G/s). Here each block
// owns (chunk, edge-segment): counts its segment's dsts that fall in its
// 12544-counter chunk via LDS ds_add, then writes the partial out coalesced,
// non-atomic. Exactly-once by construction; no dispatch-order assumptions.
__global__ __launch_bounds__(256) void hist_part_kernel(
        const int* __restrict__ ci, const int* __restrict__ vi,
        int* __restrict__ partC, int* __restrict__ partV, int E) {
    __shared__ int lh[HCHUNK];
    const int seg  = blockIdx.x % HSEG;
    const int cg   = blockIdx.x / HSEG;
    const bool isC = cg < HCHC;
    const int chunk = isC ? cg : cg - HCHC;
    const int base  = chunk * HCHUNK;
    const int* __restrict__ dst = isC ? ci : vi;
    int* __restrict__ part = (isC ? partC : partV) + (size_t)(chunk * HSEG + seg) * HCHUNK;

    int4* l4 = (int4*)lh;
    for (int i = threadIdx.x; i < HCHUNK / 4; i += 256) l4[i] = make_int4(0, 0, 0, 0);
    __syncthreads();

    const int s0 = (int)((long long)seg * E / HSEG);
    const int s1 = (int)((long long)(seg + 1) * E / HSEG);
    for (int i = s0 + threadIdx.x; i < s1; i += 256) {
        const unsigned rel = (unsigned)(dst[i] - base);
        if (rel < (unsigned)HCHUNK) atomicAdd(&lh[rel], 1);
    }
    __syncthreads();
    int4* p4 = (int4*)part;
    for (int i = threadIdx.x; i < HCHUNK / 4; i += 256) p4[i] = l4[i];
}

// sum the HSEG segment-partials per counter -> degC/degV (coalesced reads)
__global__ __launch_bounds__(256) void hist_reduce_kernel(
        const int* __restrict__ partC, const int* __restrict__ partV,
        int* __restrict__ degC, int* __restrict__ degV) {
    int j = blockIdx.x * blockDim.x + threadIdx.x;
    const int tot = NCON + NVAR;
    for (; j < tot; j += gridDim.x * blockDim.x) {
        if (j < NCON) {
            const int chunk = j / HCHUNK, off = j - chunk * HCHUNK;
            const int* p = partC + (size_t)chunk * HSEG * HCHUNK + off;
            int s = 0;
#pragma unroll
            for (int t = 0; t < HSEG; ++t) s += p[(size_t)t * HCHUNK];
            degC[j] = s;
        } else {
            const int jj = j - NCON;
            const int chunk = jj / HCHUNK, off = jj - chunk * HCHUNK;
            const int* p = partV + (size_t)chunk * HSEG * HCHUNK + off;
            int s = 0;
#pragma unroll
            for (int t = 0; t < HSEG; ++t) s += p[(size_t)t * HCHUNK];
            degV[jj] = s;
        }
    }
}

// fallback: atomic histogram (used only if ws can't fit the partials)
__global__ __launch_bounds__(256) void hist2_kernel(
        const int* __restrict__ ci, const int* __restrict__ vi,
        int* __restrict__ degC, int* __restrict__ degV, int E) {
    int i = blockIdx.x * blockDim.x + threadIdx.x;
    for (; i < E; i += gridDim.x * blockDim.x) {
        atomicAdd(&degC[ci[i]], 1);
        atomicAdd(&degV[vi[i]], 1);
    }
}

template <bool PAD>
__global__ __launch_bounds__(256) void chunk_sum_kernel(const int* __restrict__ hist,
                                                        int* __restrict__ csum, int N) {
    __shared__ int wpart[4];
    const int base = blockIdx.x * 1024 + threadIdx.x * 4;
    int s = 0;
    if (base + 3 < N) {
        int4 t = *(const int4*)(hist + base);
        if (PAD) s = ((t.x+15)&~15) + ((t.y+15)&~15) + ((t.z+15)&~15) + ((t.w+15)&~15);
        else     s = t.x + t.y + t.z + t.w;
    } else {
#pragma unroll
        for (int j = 0; j < 4; ++j)
            if (base + j < N) { int v = hist[base + j]; s += PAD ? ((v+15)&~15) : v; }
    }
    s = wtotal64_i(s);
    if ((threadIdx.x & 63) == 0) wpart[threadIdx.x >> 6] = s;
    __syncthreads();
    if (threadIdx.x == 0) csum[blockIdx.x] = wpart[0] + wpart[1] + wpart[2] + wpart[3];
}

__global__ void chunk_offsets_kernel(const int* __restrict__ csum, int* __restrict__ coff,
                                     int* __restrict__ rowptr, int nchunk, int N) {
    const int lane = threadIdx.x;
    int carry = 0;
    for (int base = 0; base < nchunk; base += 64) {
        const int i = base + lane;
        int val = (i < nchunk) ? csum[i] : 0;
        int incl = val;
#pragma unroll
        for (int off = 1; off < 64; off <<= 1) {
            int t = __shfl_up(incl, off, 64);
            if (lane >= off) incl += t;
        }
        if (i < nchunk) coff[i] = incl - val + carry;
        carry += __shfl(incl, 63, 64);
    }
    if (lane == 0) rowptr[N] = carry;
}

template <bool PAD>
__global__ __launch_bounds__(256) void chunk_apply_kernel(
        const int* __restrict__ hist, const int* __restrict__ coff,
        int* __restrict__ rowptr, int* __restrict__ cursor, int N) {
    __shared__ int wpart[4];
    const int wv = threadIdx.x >> 6;
    const int lane = threadIdx.x & 63;
    const int base = blockIdx.x * 1024 + threadIdx.x * 4;
    int v0 = 0, v1 = 0, v2 = 0, v3 = 0;
    if (base + 3 < N) {
        int4 t = *(const int4*)(hist + base);
        v0 = t.x; v1 = t.y; v2 = t.z; v3 = t.w;
    } else {
        if (base + 0 < N) v0 = hist[base + 0];
        if (base + 1 < N) v1 = hist[base + 1];
        if (base + 2 < N) v2 = hist[base + 2];
        if (base + 3 < N) v3 = hist[base + 3];
    }
    if (PAD) { v0 = (v0+15)&~15; v1 = (v1+15)&~15; v2 = (v2+15)&~15; v3 = (v3+15)&~15; }
    const int s = v0 + v1 + v2 + v3;
    int incl = s;
#pragma unroll
    for (int off = 1; off < 64; off <<= 1) {
        int t = __shfl_up(incl, off, 64);
        if (lane >= off) incl += t;
    }
    if (lane == 63) wpart[wv] = incl;
    __syncthreads();
    int excl = coff[blockIdx.x] + incl - s;
    for (int w = 0; w < wv; ++w) excl += wpart[w];
    if (base + 0 < N) { rowptr[base + 0] = excl; cursor[base + 0] = excl; excl += v0; }
    if (base + 1 < N) { rowptr[base + 1] = excl; cursor[base + 1] = excl; excl += v1; }
    if (base + 2 < N) { rowptr[base + 2] = excl; cursor[base + 2] = excl; excl += v2; }
    if (base + 3 < N) { rowptr[base + 3] = excl; cursor[base + 3] = excl; excl += v3; }
}

// XCD-bucketed scatter, ONE direction per launch. 8 dst-buckets; bucket =
// blockIdx&7 aligns with the %8 block->XCD round-robin, so each XCD's L2
// holds exactly one bucket's CSR write region: epC/8 ~= 2.35 MB or epV/8 ~=
// 3.1 MB, both < 4 MB L2/XCD. Separate launches are the hard temporal
// barrier (phases inside one launch overlap as blocks retire gradually).
// Locality heuristic only; correctness holds under any block->XCD mapping.
template <int NDST>
__global__ __launch_bounds__(256) void scatter_dir_kernel(
        const int* __restrict__ dst, const int* __restrict__ src,
        const float* __restrict__ ef,
        int* __restrict__ cur, int2* __restrict__ ep, int E) {
    const int rep = blockIdx.x & 7;
    const int stride = (gridDim.x >> 3) * blockDim.x;
    int i = (blockIdx.x >> 3) * blockDim.x + threadIdx.x;
    for (; i < E; i += stride) {
        const int d = dst[i];
        const int b = (int)(((long long)d * 8) / NDST);
        if (b == rep) {
            const int slot = atomicAdd(&cur[d], 1);
            ep[slot] = make_int2(src[i], __float_as_int(ef[i]));
        }
    }
}

// ---------------- fused node linear: RL segment + LL segment -> f16 ----------------

__global__ __launch_bounds__(256, 4) void lin2_kernel(
        const float* __restrict__ XR, const float* __restrict__ WR,
        const float* __restrict__ bR, _Float16* __restrict__ YR, int NR,
        const float* __restrict__ XL, const float* __restrict__ WL,
        _Float16* __restrict__ YL, int NL, int nbR) {
    __shared__ __align__(16) _Float16 xbuf[4][EMB];
    const int wv = threadIdx.x >> 6;
    const int lane = threadIdx.x & 63;
    const bool isR = (int)blockIdx.x < nbR;
    const float* X = isR ? XR : XL;
    _Float16* Y    = isR ? YR : YL;
    const int N    = isR ? NR : NL;
    const int b0   = isR ? 0 : nbR;
    const int nb   = isR ? nbR : (gridDim.x - nbR);
    half2_t wh[32];
    load_w_f16(isR ? WR : WL, EMB, lane, wh);
    const float bias = isR ? bR[lane] : 0.0f;
    const int nW = nb * 4;
    for (int n = ((int)blockIdx.x - b0) * 4 + wv; n < N; n += nW) {
        xbuf[wv][lane] = (_Float16)X[(size_t)n * EMB + lane];
        Y[(size_t)n * EMB + lane] = (_Float16)matvec_f16(xbuf[wv], wh, bias);
    }
}

// ---------------- edge stage: wave per node, abar accumulate, Wf once/node ----------------
// Key identity: sum_e relu(LN(h_e)) @ Wf^T = (sum_e relu(LN(h_e))) @ Wf^T  (matvec is linear).

__global__ __launch_bounds__(256, 4) void edge_abar_kernel(
        const int* __restrict__ rp16, const int* __restrict__ deg,
        const int2* __restrict__ ep,
        const _Float16* __restrict__ RL, const _Float16* __restrict__ LL,
        const float* __restrict__ We, const float* __restrict__ g1,
        const float* __restrict__ b1, const float* __restrict__ Wf,
        const float* __restrict__ bfp, _Float16* __restrict__ AGG, int Nr) {
    __shared__ __align__(16) _Float16 abuf[4][EMB];
    const int wv   = threadIdx.x >> 6;
    const int lane = threadIdx.x & 63;
    const int col  = lane & 15;
    const int quad = lane >> 4;
    const int kb   = quad * 8;

    half2_t weh[8], gkh[8], bkh[8];
#pragma unroll
    for (int j = 0; j < 4; ++j) {
        weh[j]     = half2_t{(_Float16)We[kb + 2*j],      (_Float16)We[kb + 2*j + 1]};
        weh[4 + j] = half2_t{(_Float16)We[kb + 32 + 2*j], (_Float16)We[kb + 32 + 2*j + 1]};
        gkh[j]     = half2_t{(_Float16)g1[kb + 2*j],      (_Float16)g1[kb + 2*j + 1]};
        gkh[4 + j] = half2_t{(_Float16)g1[kb + 32 + 2*j], (_Float16)g1[kb + 32 + 2*j + 1]};
        bkh[j]     = half2_t{(_Float16)b1[kb + 2*j],      (_Float16)b1[kb + 2*j + 1]};
        bkh[4 + j] = half2_t{(_Float16)b1[kb + 32 + 2*j], (_Float16)b1[kb + 32 + 2*j + 1]};
    }
    half2_t whF[32];
    load_w_f16(Wf, EMB, lane, whF);
    const float bfv = bfp[lane];

    const int nW = gridDim.x * 4;
    for (int n = blockIdx.x * 4 + wv; n < Nr; n += nW) {
        const int g0  = rp16[n] >> 4;
        const int g1e = rp16[n + 1] >> 4;
        const int dn  = deg[n];
        half2_t rl2[8];
        *(f16x8*)&rl2[0] = *(const f16x8*)(RL + (size_t)n * EMB + kb);
        *(f16x8*)&rl2[4] = *(const f16x8*)(RL + (size_t)n * EMB + kb + 32);
        float acc[16];
#pragma unroll
        for (int j = 0; j < 16; ++j) acc[j] = 0.0f;

        if (g0 < g1e) {
            // prefetch first group
            bool livN = col < dn;
            int2 p = ep[(g0 << 4) + col];
            int sN = livN ? p.x : 0;
            float fN = livN ? __int_as_float(p.y) : 0.0f;
            f16x8 llaN = *(const f16x8*)(LL + (size_t)sN * EMB + kb);
            f16x8 llbN = *(const f16x8*)(LL + (size_t)sN * EMB + kb + 32);

            for (int g = g0; g < g1e; ++g) {
                const bool liv = livN;
                const float f = fN;
                half2_t h2[8];
                *(f16x8*)&h2[0] = llaN;
                *(f16x8*)&h2[4] = llbN;
                if (g + 1 < g1e) {
                    const int cnt = dn - ((g + 1 - g0) << 4);
                    livN = col < cnt;
                    p = ep[((g + 1) << 4) + col];
                    const int s2 = livN ? p.x : 0;
                    fN = livN ? __int_as_float(p.y) : 0.0f;
                    llaN = *(const f16x8*)(LL + (size_t)s2 * EMB + kb);
                    llbN = *(const f16x8*)(LL + (size_t)s2 * EMB + kb + 32);
                }
                const _Float16 fh = (_Float16)f;
                const half2_t f2 = half2_t{fh, fh};
                const half2_t one2 = half2_t{(_Float16)1.0f, (_Float16)1.0f};
                float ps = 0.0f, pq = 0.0f;
#pragma unroll
                for (int j = 0; j < 8; ++j) {
                    h2[j] = (h2[j] + rl2[j]) + f2 * weh[j];
                    ps = dot2f(h2[j], one2, ps);
                    pq = dot2f(h2[j], h2[j], pq);
                }
                ps += __shfl_xor(ps, 16, 64); ps += __shfl_xor(ps, 32, 64);
                pq += __shfl_xor(pq, 16, 64); pq += __shfl_xor(pq, 32, 64);
                const float mean = ps * (1.0f / EMB);
                const float var  = pq * (1.0f / EMB) - mean * mean;
                const float rs   = rsqrtf(var + EPSLN);
                const _Float16 rsh = (_Float16)rs;
                const _Float16 mnh = (_Float16)mean;
                const half2_t rs2 = half2_t{rsh, rsh};
                const half2_t mn2 = half2_t{mnh, mnh};
                const half2_t z2  = half2_t{(_Float16)0.0f, (_Float16)0.0f};
                if (liv) {
#pragma unroll
                    for (int j = 0; j < 8; ++j) {
                        const half2_t sc = gkh[j] * rs2;
                        half2_t a = (h2[j] - mn2) * sc + bkh[j];
                        a = hmax2(a, z2);
                        acc[2*j]   += (float)a.x;
                        acc[2*j+1] += (float)a.y;
                    }
                }
            }
        }
        // reduce abar partials across the 16 cols of each quad
#pragma unroll
        for (int st = 1; st < 16; st <<= 1) {
#pragma unroll
            for (int j = 0; j < 16; ++j)
                acc[j] += __shfl_xor(acc[j], st, 64);
        }
        // lane's element of abar: acc[col] maps to k = (col<8) ? kb+col : kb+32+(col-8)
        abuf[wv][(col < 8) ? (kb + col) : (kb + 24 + col)] = (_Float16)acc[col];
        // agg = abar @ Wf^T + deg*bf   (one matvec per node)
        AGG[(size_t)n * EMB + lane] = (_Float16)matvec_f16(abuf[wv], whF, (float)dn * bfv);
    }
}

// ---------------- fallback edge path (wave per node, dot2, f16 RL/LL) ----------------

__global__ __launch_bounds__(256, 4) void edge_csr_kernel(
        const int* __restrict__ rowptr, const int2* __restrict__ ep,
        const _Float16* __restrict__ RL, const _Float16* __restrict__ LL,
        const float* __restrict__ Wecol, const float* __restrict__ g1,
        const float* __restrict__ b1,
        const float* __restrict__ Wf, const float* __restrict__ bfp,
        _Float16* __restrict__ AGG, int Nr) {
    __shared__ __align__(16) _Float16 hbuf[4][EMB];
    const int wv = threadIdx.x >> 6;
    const int lane = threadIdx.x & 63;
    half2_t wh[32];
    load_w_f16(Wf, EMB, lane, wh);
    const float we  = Wecol[lane];
    const float g   = g1[lane];
    const float bb  = b1[lane];
    const float bf_ = bfp[lane];
    const int nW = gridDim.x * 4;
    for (int n = blockIdx.x * 4 + wv; n < Nr; n += nW) {
        const int beg = rowptr[n];
        const int end = rowptr[n + 1];
        const float rl = (float)RL[(size_t)n * EMB + lane];
        float acc = 0.0f;
        for (int idx = beg; idx < end; ++idx) {
            const int2 p = ep[idx];
            const float f = __int_as_float(p.y);
            float h = rl + (float)LL[(size_t)p.x * EMB + lane] + f * we;
            const float s1 = wtotal64(h);
            const float s2 = wtotal64(h * h);
            const float m   = s1 * (1.0f / EMB);
            const float var = s2 * (1.0f / EMB) - m * m;
            float hn = fmaxf((h - m) * rsqrtf(var + EPSLN) * g + bb, 0.0f);
            hbuf[wv][lane] = (_Float16)hn;
            acc = matvec_f16(hbuf[wv], wh, acc);
        }
        AGG[(size_t)n * EMB + lane] = (_Float16)(acc + (float)(end - beg) * bf_);
    }
}

// ---------------- fused output MLP ----------------
// z = LN(AGG); o = relu(Wo1a@z + Wo1b@right + bo1); right += Wo2@o + bo2

__global__ __launch_bounds__(256, 3) void out_kernel(
        const _Float16* __restrict__ AGG, float* __restrict__ right,
        const float* __restrict__ g2, const float* __restrict__ b2,
        const float* __restrict__ Wo1, const float* __restrict__ Wo2,
        const float* __restrict__ bo1, const float* __restrict__ bo2, int N) {
    __shared__ __align__(16) _Float16 zbuf[4][EMB];
    __shared__ __align__(16) _Float16 rbuf[4][EMB];
    __shared__ __align__(16) _Float16 obuf[4][EMB];
    const int wv = threadIdx.x >> 6;
    const int lane = threadIdx.x & 63;
    half2_t wh1[32], whB[32], wh2[32];
    load_w_f16(Wo1, 2 * EMB, lane, wh1);            // Wo1[:, 0:64]
    load_w_f16(Wo1 + EMB, 2 * EMB, lane, whB);      // Wo1[:, 64:128]
    load_w_f16(Wo2, EMB, lane, wh2);
    const float g    = g2[lane];
    const float bb   = b2[lane];
    const float bo1v = bo1[lane];
    const float bo2v = bo2[lane];
    const int nW = gridDim.x * 4;
    for (int n = blockIdx.x * 4 + wv; n < N; n += nW) {
        const float a = (float)AGG[(size_t)n * EMB + lane];
        const float rf = right[(size_t)n * EMB + lane];
        const float s1 = wtotal64(a);
        const float s2 = wtotal64(a * a);
        const float m   = s1 * (1.0f / EMB);
        const float var = s2 * (1.0f / EMB) - m * m;
        const float z = (a - m) * rsqrtf(var + EPSLN) * g + bb;
        zbuf[wv][lane] = (_Float16)z;
        rbuf[wv][lane] = (_Float16)rf;
        float acc = matvec_f16(zbuf[wv], wh1, bo1v);
        acc = matvec_f16(rbuf[wv], whB, acc);
        obuf[wv][lane] = (_Float16)fmaxf(acc, 0.0f);
        float acc2 = matvec_f16(obuf[wv], wh2, bo2v);
        right[(size_t)n * EMB + lane] = rf + acc2;
    }
}

extern "C" void kernel_launch(void* const* d_in, const int* in_sizes, int n_in,
                              void* d_out, int out_size, void* d_ws, size_t ws_size,
                              hipStream_t stream) {
    const float* cf  = (const float*)d_in[0];
    const float* vfp = (const float*)d_in[1];
    const int*   ei  = (const int*)d_in[2];
    const float* ef  = (const float*)d_in[3];
    const float* Wl  = (const float*)d_in[4];
    const float* bl  = (const float*)d_in[5];
    const float* We  = (const float*)d_in[6];
    const float* Wr  = (const float*)d_in[7];
    const float* g1  = (const float*)d_in[8];
    const float* b1  = (const float*)d_in[9];
    const float* Wf  = (const float*)d_in[10];
    const float* bfp = (const float*)d_in[11];
    const float* g2  = (const float*)d_in[12];
    const float* b2  = (const float*)d_in[13];
    const float* Wo1 = (const float*)d_in[14];
    const float* bo1 = (const float*)d_in[15];
    const float* Wo2 = (const float*)d_in[16];
    const float* bo2 = (const float*)d_in[17];

    float* c = (float*)d_out;
    float* v = c + (size_t)NCON * EMB;
    (void)hipMemcpyAsync(c, cf,  (size_t)NCON * EMB * sizeof(float), hipMemcpyDeviceToDevice, stream);
    (void)hipMemcpyAsync(v, vfp, (size_t)NVAR * EMB * sizeof(float), hipMemcpyDeviceToDevice, stream);

    float* wsf = (float*)d_ws;
    size_t off = 0;
    _Float16* AGG = (_Float16*)(wsf + off); off += (size_t)NVAR * EMB / 2;  // f16
    _Float16* RL  = (_Float16*)(wsf + off); off += (size_t)NVAR * EMB / 2;  // f16
    _Float16* LL  = (_Float16*)(wsf + off); off += (size_t)NVAR * EMB / 2;  // f16
    int* degC  = (int*)(wsf + off); off += NCON;
    int* degV  = (int*)(wsf + off); off += NVAR;
    int* rp16C = (int*)(wsf + off); off += NCON + 4;
    int* curC  = (int*)(wsf + off); off += NCON;
    int* rp16V = (int*)(wsf + off); off += NVAR + 4;
    int* curV  = (int*)(wsf + off); off += NVAR;
    int* csumC = (int*)(wsf + off); off += 128;
    int* coffC = (int*)(wsf + off); off += 128;
    int* csumV = (int*)(wsf + off); off += 128;
    int* coffV = (int*)(wsf + off); off += 128;
    size_t off_edges = off;
    int2* epC = (int2*)(wsf + off); off += (size_t)2 * PADEC;
    int2* epV = (int2*)(wsf + off); off += (size_t)2 * PADEV;
    const bool use_mfma = ws_size >= off * sizeof(float);
    // histogram partials (19.3 MB) after the edge arrays
    int* partC = (int*)(wsf + off); off += (size_t)HCHC * HSEG * HCHUNK;
    int* partV = (int*)(wsf + off); off += (size_t)HCHV * HSEG * HCHUNK;
    const bool use_ldshist = use_mfma && ws_size >= off * sizeof(float);
    if (!use_mfma) {
        off = off_edges;
        epC = (int2*)(wsf + off); off += (size_t)2 * NEDGE;
        epV = (int2*)(wsf + off); off += (size_t)2 * NEDGE;
    }

    const int* ci = ei;
    const int* vi = ei + NEDGE;

    const dim3 blk(256);
    const int NB = 2048;
    const int NBL = 1536;
    const int nchC = (NCON + 1023) / 1024;   // 49
    const int nchV = (NVAR + 1023) / 1024;   // 98

    if (use_ldshist) {
        hist_part_kernel<<<(HCHC + HCHV) * HSEG, blk, 0, stream>>>(ci, vi, partC, partV, NEDGE);
        hist_reduce_kernel<<<640, blk, 0, stream>>>(partC, partV, degC, degV);
    } else {
        (void)hipMemsetAsync(degC, 0, NCON * sizeof(int), stream);
        (void)hipMemsetAsync(degV, 0, NVAR * sizeof(int), stream);
        hist2_kernel<<<1024, blk, 0, stream>>>(ci, vi, degC, degV, NEDGE);
    }
    if (use_mfma) {
        chunk_sum_kernel<true><<<nchC, blk, 0, stream>>>(degC, csumC, NCON);
        chunk_sum_kernel<true><<<nchV, blk, 0, stream>>>(degV, csumV, NVAR);
        chunk_offsets_kernel<<<1, 64, 0, stream>>>(csumC, coffC, rp16C, nchC, NCON);
        chunk_offsets_kernel<<<1, 64, 0, stream>>>(csumV, coffV, rp16V, nchV, NVAR);
        chunk_apply_kernel<true><<<nchC, blk, 0, stream>>>(degC, coffC, rp16C, curC, NCON);
        chunk_apply_kernel<true><<<nchV, blk, 0, stream>>>(degV, coffV, rp16V, curV, NVAR);
    } else {
        chunk_sum_kernel<false><<<nchC, blk, 0, stream>>>(degC, csumC, NCON);
        chunk_sum_kernel<false><<<nchV, blk, 0, stream>>>(degV, csumV, NVAR);
        chunk_offsets_kernel<<<1, 64, 0, stream>>>(csumC, coffC, rp16C, nchC, NCON);
        chunk_offsets_kernel<<<1, 64, 0, stream>>>(csumV, coffV, rp16V, nchV, NVAR);
        chunk_apply_kernel<false><<<nchC, blk, 0, stream>>>(degC, coffC, rp16C, curC, NCON);
        chunk_apply_kernel<false><<<nchV, blk, 0, stream>>>(degV, coffV, rp16V, curV, NVAR);
    }
    // one direction per launch: hard temporal separation so each XCD's L2
    // holds only that direction's bucket region (C: 2.35 MB, V: 3.1 MB).
    scatter_dir_kernel<NCON><<<2048, blk, 0, stream>>>(ci, vi, ef, curC, epC, NEDGE);
    scatter_dir_kernel<NVAR><<<2048, blk, 0, stream>>>(vi, ci, ef, curV, epV, NEDGE);

    for (int k = 0; k < 4; ++k) {
        const bool v2c = ((k & 1) == 0);
        float* right   = v2c ? c : v;
        float* left    = v2c ? v : c;
        const int Nr   = v2c ? NCON : NVAR;
        const int Nl   = v2c ? NVAR : NCON;
        const int nbR  = v2c ? NBL / 3 : 2 * NBL / 3;   // split blocks ~ Nr : Nl

        lin2_kernel<<<NBL, blk, 0, stream>>>(
            right, Wl + (size_t)k * EMB * EMB, bl + (size_t)k * EMB, RL, Nr,
            left,  Wr + (size_t)k * EMB * EMB, LL, Nl, nbR);

        if (use_mfma) {
            edge_abar_kernel<<<NB, blk, 0, stream>>>(
                v2c ? rp16C : rp16V, v2c ? degC : degV, v2c ? epC : epV,
                RL, LL, We + (size_t)k * EMB,
                g1 + (size_t)k * EMB, b1 + (size_t)k * EMB,
                Wf + (size_t)k * EMB * EMB, bfp + (size_t)k * EMB, AGG, Nr);
        } else {
            edge_csr_kernel<<<NB, blk, 0, stream>>>(
                v2c ? rp16C : rp16V, v2c ? epC : epV,
                RL, LL, We + (size_t)k * EMB,
                g1 + (size_t)k * EMB, b1 + (size_t)k * EMB,
                Wf + (size_t)k * EMB * EMB, bfp + (size_t)k * EMB, AGG, Nr);
        }
        out_kernel<<<NB, blk, 0, stream>>>(AGG, right,
                                           g2 + (size_t)k * EMB, b2 + (size_t)k * EMB,
                                           Wo1 + (size_t)k * EMB * 2 * EMB,
                                           Wo2 + (size_t)k * EMB * EMB,
                                           bo1 + (size_t)k * EMB, bo2 + (size_t)k * EMB,
                                           Nr);
    }
}